// Round 1
// 180.174 us; speedup vs baseline: 1.0561x; 1.0561x over previous
//
#include <hip/hip_runtime.h>
#include <type_traits>

#define NODE 400
#define POP 3
#define TRS 40
#define STEPS 10
#define DMAX 500
#define OUT 64
#define DT 0.1f
#define JPL 7           // ceil(NODE/64) j-indices per lane
#define WSTR 512        // per-stream W bin stride (delta in [0,511])

__device__ __forceinline__ float relu_(float x) { return x > 0.f ? x : 0.f; }
__device__ __forceinline__ float rcp_(float x) { return __builtin_amdgcn_rcpf(x); }
__device__ __forceinline__ float rlane_(float v, int l) {
  return __builtin_bit_cast(float, __builtin_amdgcn_readlane(__builtin_bit_cast(int, v), l));
}

// ---- DPP helpers
template <int CTRL>
__device__ __forceinline__ float dpp_mov(float x) {
  int r = __builtin_amdgcn_update_dpp(0, __builtin_bit_cast(int, x), CTRL,
                                      0xf, 0xf, true);
  return __builtin_bit_cast(float, r);
}
template <int CTRL>
__device__ __forceinline__ int dpp_movi(int x) {
  return __builtin_amdgcn_update_dpp(0, x, CTRL, 0xf, 0xf, true);
}
// wave rotate-left-by-1: dst[L] = src[(L+1) & 63]  (wave_rol:1 = 0x134)
__device__ __forceinline__ float wrol1(float x) { return dpp_mov<0x134>(x); }

__device__ __forceinline__ void wave_reduce3(float& a, float& b, float& c) {
  a += dpp_mov<0x111>(a); b += dpp_mov<0x111>(b); c += dpp_mov<0x111>(c);
  a += dpp_mov<0x112>(a); b += dpp_mov<0x112>(b); c += dpp_mov<0x112>(c);
  a += dpp_mov<0x114>(a); b += dpp_mov<0x114>(b); c += dpp_mov<0x114>(c);
  a += dpp_mov<0x118>(a); b += dpp_mov<0x118>(b); c += dpp_mov<0x118>(c);
  a += dpp_mov<0x142>(a); b += dpp_mov<0x142>(b); c += dpp_mov<0x142>(c);
  a += dpp_mov<0x143>(a); b += dpp_mov<0x143>(b); c += dpp_mov<0x143>(c);
  a = rlane_(a, 63); b = rlane_(b, 63); c = rlane_(c, 63);
}

__device__ __forceinline__ int wave_max_int(int x) {
  x = max(x, dpp_movi<0x111>(x));
  x = max(x, dpp_movi<0x112>(x));
  x = max(x, dpp_movi<0x114>(x));
  x = max(x, dpp_movi<0x118>(x));
  x = max(x, dpp_movi<0x142>(x));
  x = max(x, dpp_movi<0x143>(x));
  return __builtin_amdgcn_readlane(x, 63);
}

// ---------------------------------------------------------------------------
// Kernel A: Frobenius sum-of-squares partials (64 blocks, no atomics).
// ---------------------------------------------------------------------------
__global__ __launch_bounds__(256) void ssq_kernel(
    const float* __restrict__ wbb, const float* __restrict__ wff,
    const float* __restrict__ wll, const float* __restrict__ sc,
    float* __restrict__ part) {
  float eb = 0.f, ef = 0.f, el = 0.f;
  for (int idx = blockIdx.x * 256 + threadIdx.x; idx < NODE * NODE;
       idx += 64 * 256) {
    int i = idx / NODE, j = idx - i * NODE;
    int ji = j * NODE + i;
    float scij = sc[idx];
    float b = expf(wbb[idx]) * scij;
    float f = expf(wff[idx]) * scij;
    float l = 0.5f * (expf(wll[idx]) * scij + expf(wll[ji]) * sc[ji]);
    eb = fmaf(b, b, eb); ef = fmaf(f, f, ef); el = fmaf(l, l, el);
  }
  wave_reduce3(eb, ef, el);
  __shared__ float red[3][4];
  int lane = threadIdx.x & 63, wv = threadIdx.x >> 6;
  if (lane == 0) { red[0][wv] = eb; red[1][wv] = ef; red[2][wv] = el; }
  __syncthreads();
  if (threadIdx.x == 0) {
    part[blockIdx.x]       = red[0][0] + red[0][1] + red[0][2] + red[0][3];
    part[64 + blockIdx.x]  = red[1][0] + red[1][1] + red[1][2] + red[1][3];
    part[128 + blockIdx.x] = red[2][0] + red[2][1] + red[2][2] + red[2][3];
  }
}

// ---------------------------------------------------------------------------
// Kernel B: per-node simulation, SCATTER form with ROTATING accumulator.
// Slot D = lane + 64k of P always holds the partial for step t+D (at the
// start of step t). Harvest = readlane(P[0], 0) (immediate lane). Each step:
// rotate P down one lane via DPP wave_rol:1 (lane63 takes next bank's wrap),
// then scatter P[k] += W[lane+64k] * s(t) with W held in STATIC registers.
// No LDS in the time loop, no dynamic-lane readlane, no W0 special case.
// The 6 sigmoid/mN transcendental args are packed into lanes 0..5 so one
// v_exp + one v_rcp per step replaces six of each; results are read back
// with immediate-lane readlanes.
// ---------------------------------------------------------------------------
__global__ __launch_bounds__(64) void sim_kernel(
    const float* __restrict__ external, const float* __restrict__ hx,
    const float* __restrict__ hE, const float* __restrict__ sc,
    const float* __restrict__ dist, const float* __restrict__ wbb,
    const float* __restrict__ wff, const float* __restrict__ wll,
    const float* __restrict__ theta, const float* __restrict__ part,
    float* __restrict__ vsnap) {
  const int node = blockIdx.x;
  const int lane = threadIdx.x;

  __shared__ float Wall[3 * WSTR];   // Wl | Wf | Wb delay bins
  __shared__ float hE_lds[DMAX];
  __shared__ float u_lds[STEPS * TRS];

  // --- global norm sums from ssq partials (one DPP reduce) ---
  float sb = part[lane], sf = part[64 + lane], sl = part[128 + lane];
  wave_reduce3(sb, sf, sl);
  const float inv_nb = 1.f / sqrtf(sb);
  const float inv_nf = 1.f / sqrtf(sf);
  const float inv_nl = 1.f / sqrtf(sl);

  // --- parameters ---
  const float VL = relu_(theta[0]), VI = relu_(theta[1]);
  const float VE = relu_(theta[2]), VNMDA = relu_(theta[3]);
  const float alpha_mg = relu_(theta[4]), VR = relu_(theta[5]);
  const float pi_sigma = relu_(theta[6]);
  const float gLp = relu_(theta[7]), Cc = relu_(theta[8]), kappa = relu_(theta[9]);
  const float g_gE = relu_(theta[10]), g_gE_sc = relu_(theta[11]);
  const float g_gI = relu_(theta[12]), g_gI_sc = relu_(theta[13]);
  const float g_gN = relu_(theta[14]), g_gN_sc = relu_(theta[15]);
  const float g_k = relu_(theta[16]);
  const float mu = 0.1f + relu_(theta[20]);
  const float uk = relu_(theta[21]) * theta[23];
  const float g_l = relu_(theta[24]), g_f = relu_(theta[25]), g_b = relu_(theta[26]);
  const float DTC = DT / Cc;
  const float dk = DT * kappa;
  const float nps = -pi_sigma, psVR = pi_sigma * VR;
  const float nam = -alpha_mg;

  // pre-scaled dynamics constants (dk folded in)
  const float dk1  = 1.f - dk;
  const float cA   = dk * g_l;
  const float cF   = dk * g_f;
  const float cB   = dk * g_b;
  const float cE0s = dk * g_gE;
  const float cE1e = dk * g_gE_sc;
  const float cE2e = dk * g_k;
  const float cI0  = dk * g_gI;
  const float cI1  = dk * g_gI_sc;
  const float cN0s = dk * g_gN;
  const float cN1  = dk * g_gN_sc;
  const float cN2  = dk * g_gN;
  const float gLVL = gLp * VL;

  // --- stage LDS: zero W bins, history, pre-scaled external drive ---
  for (int k = lane; k < 3 * WSTR; k += 64) Wall[k] = 0.f;
  for (int d = lane; d < DMAX; d += 64) hE_lds[d] = hE[node * DMAX + d];
  const float ukdk = dk * uk;
  for (int t = lane; t < STEPS * TRS; t += 64)
    u_lds[t] = ukdk * external[node * STEPS * TRS + t];

  // --- bin weights by delay (LDS float atomics), row sums, max delay ---
  float rl = 0.f, rf = 0.f, rb = 0.f;
  int mymax = 0;
#pragma unroll
  for (int kj = 0; kj < JPL; ++kj) {
    int j = lane + kj * 64;
    if (j < NODE) {
      int ij = node * NODE + j;
      int ji = j * NODE + node;
      float scij = sc[ij];
      float vb = expf(wbb[ij]) * scij * inv_nb;
      float vf = expf(wff[ij]) * scij * inv_nf;
      float vl = 0.5f * (expf(wll[ij]) * scij + expf(wll[ji]) * sc[ji]) * inv_nl;
      int dd = (int)(dist[ij] / mu);
      dd = min(max(dd, 0), DMAX - 1);
      atomicAdd(&Wall[dd], vl);
      atomicAdd(&Wall[WSTR + dd], vf);
      atomicAdd(&Wall[2 * WSTR + dd], vb);
      rl += vl; rf += vf; rb += vb;
      mymax = max(mymax, dd);
    }
  }
  wave_reduce3(rl, rf, rb);
  const float rs_l = rl, rs_f = rf, rs_b = rb;
  const int maxd = wave_max_int(mymax);
  const int nb = (maxd >> 6) + 1;   // banks needed (<=8 since maxd<=499)

  const float cE0s2 = cE0s - cA * rs_l;    // sP coefficients, lr folded
  const float cN0s2 = cN0s - cA * rs_l;
  const float cE1s = -cB * rs_b;
  const float cE2s = -cF * rs_f;

  // --- initial state (replicated across lanes) ---
  const int hb = node * POP * 4;
  float V0 = hx[hb + 0], V1 = hx[hb + 4], V2 = hx[hb + 8];
  float E0 = hx[hb + 1], E1 = hx[hb + 5], E2 = hx[hb + 9];
  float I0 = hx[hb + 2], I1 = hx[hb + 6], I2 = hx[hb + 10];
  float N0 = hx[hb + 3], N1 = hx[hb + 7], N2 = hx[hb + 11];

  // --- packed-transcendental lane constants (lanes 0-5 meaningful):
  // lane 0..2: sigmoid args for V0,V1,V2 ; lane 3..5: mN exp args for V0,V1,V2
  const float L2E = 1.44269504088896f;
  const bool loS = (lane < 3);
  const float caL = loS ? nps * L2E : nam * L2E;
  const float cbL = loS ? psVR * L2E : 0.f;
  const float cdL = loS ? 1.f : 0.2f;
  const bool selB = (lane == 1) || (lane == 4);
  const bool selC = (lane == 2) || (lane == 5);
  const bool is63 = (lane == 63);

  auto core = [&](auto nbtag) {
    constexpr int NB = decltype(nbtag)::value;
    // --- prologue: history contributions. Slot D = lane + 64k holds the
    // partial for step D (start of step 0): P[D] = sum_{d>=D} W[d]*hE[d-D].
    float Pl[NB], Pf[NB], Pb[NB];
#pragma unroll
    for (int k = 0; k < NB; ++k) { Pl[k] = 0.f; Pf[k] = 0.f; Pb[k] = 0.f; }
    for (int d = 0; d <= maxd; ++d) {
      float wl_ = Wall[d], wf_ = Wall[WSTR + d], wb_ = Wall[2 * WSTR + d];
#pragma unroll
      for (int k = 0; k < NB; ++k) {
        int D = lane + (k << 6);
        int idx = d - D;
        bool ok = idx >= 0;
        float h = hE_lds[ok ? idx : 0];
        h = ok ? h : 0.f;
        Pl[k] = fmaf(wl_, h, Pl[k]);
        Pf[k] = fmaf(wf_, h, Pf[k]);
        Pb[k] = fmaf(wb_, h, Pb[k]);
      }
    }

    // --- static per-lane W registers: W[lane + 64k] (bins beyond maxd are 0)
    float Wl[NB], Wf[NB], Wb[NB];
#pragma unroll
    for (int k = 0; k < NB; ++k) {
      int D = lane + (k << 6);
      Wl[k] = Wall[D];
      Wf[k] = Wall[WSTR + D];
      Wb[k] = Wall[2 * WSTR + D];
    }

    for (int tr = 0; tr < TRS; ++tr) {
      float u_tr = (lane < STEPS) ? u_lds[lane * TRS + tr] : 0.f;
#pragma unroll
      for (int st = 0; st < STEPS; ++st) {
        // 1) harvest al/af/ab: slot D=0 is lane 0, bank 0 (immediate lane)
        float al = rlane_(Pl[0], 0);
        float af = rlane_(Pf[0], 0);
        float ab = rlane_(Pb[0], 0);

        // 2) packed sigmoid + mN: ONE v_exp + ONE v_rcp for all six values
        float Vs = selC ? V2 : (selB ? V1 : V0);
        float ex = __builtin_amdgcn_exp2f(fmaf(caL, Vs, cbL));
        float sg = rcp_(fmaf(cdL, ex, 1.f));
        float sE = rlane_(sg, 0), sI = rlane_(sg, 1), sP = rlane_(sg, 2);
        float m0 = rlane_(sg, 3), m1 = rlane_(sg, 4), m2 = rlane_(sg, 5);
        float U = rlane_(u_tr, st);            // already dk*uk scaled

        // 3) dynamics (replicated)
        float t1 = cA * al, t2 = cF * af, t3 = cB * ab;
        float nE0 = fmaf(dk1, E0, fmaf(cE0s2, sP, t1 + U));
        float nE1 = fmaf(dk1, E1, fmaf(cE1e, sE, fmaf(cE1s, sP, t3)));
        float nE2 = fmaf(dk1, E2, fmaf(cE2e, sE, fmaf(cE2s, sP, t2 + U)));
        float pI = cI0 * sI;
        float nI0 = fmaf(dk1, I0, pI);
        float nI1 = fmaf(dk1, I1, cI1 * sI);
        float nI2 = fmaf(dk1, I2, pI);
        float nN0 = fmaf(dk1, N0, fmaf(cN0s2, sP, t1));
        float nN1 = fmaf(dk1, N1, cN1 * sE);
        float nN2 = fmaf(dk1, N2, cN2 * sE);

        float Nm0 = N0 * m0, Nm1 = N1 * m1, Nm2 = N2 * m2;
        float R0 = fmaf(E0, VE, fmaf(Nm0, VNMDA, fmaf(I0, -VI, -gLVL)));
        float R1 = fmaf(E1, VE, fmaf(Nm1, VNMDA, fmaf(I1, -VI, -gLVL)));
        float R2 = fmaf(E2, VE, fmaf(Nm2, VNMDA, fmaf(I2, -VI, -gLVL)));
        float S0 = gLp + E0 + I0 + Nm0;
        float S1 = gLp + E1 + I1 + Nm1;
        float S2 = gLp + E2 + I2 + Nm2;
        V0 = fmaf(DTC, fmaf(-S0, V0, R0), V0);
        V1 = fmaf(DTC, fmaf(-S1, V1, R1), V1);
        V2 = fmaf(DTC, fmaf(-S2, V2, R2), V2);
        E0 = nE0; E1 = nE1; E2 = nE2;
        I0 = nI0; I1 = nI1; I2 = nI2;
        N0 = nN0; N1 = nN1; N2 = nN2;

        // 4) rotate P down one lane (slot D <- slot D+1); lane 63 of bank k
        //    takes bank k+1's wrap value (rol(bank_{k+1})[63] = bank_{k+1}[0])
        float Rl_[NB], Rf_[NB], Rb_[NB];
#pragma unroll
        for (int k = 0; k < NB; ++k) {
          Rl_[k] = wrol1(Pl[k]); Rf_[k] = wrol1(Pf[k]); Rb_[k] = wrol1(Pb[k]);
        }
#pragma unroll
        for (int k = 0; k < NB - 1; ++k) {
          Pl[k] = is63 ? Rl_[k + 1] : Rl_[k];
          Pf[k] = is63 ? Rf_[k + 1] : Rf_[k];
          Pb[k] = is63 ? Rb_[k + 1] : Rb_[k];
        }
        Pl[NB - 1] = is63 ? 0.f : Rl_[NB - 1];
        Pf[NB - 1] = is63 ? 0.f : Rf_[NB - 1];
        Pb[NB - 1] = is63 ? 0.f : Rb_[NB - 1];

        // 5) scatter s(t) with STATIC per-lane weights (no LDS)
#pragma unroll
        for (int k = 0; k < NB; ++k) {
          Pl[k] = fmaf(Wl[k], sP, Pl[k]);
          Pf[k] = fmaf(Wf[k], sP, Pf[k]);
          Pb[k] = fmaf(Wb[k], sP, Pb[k]);
        }
      }
      if (lane == 0) vsnap[tr * NODE + node] = V2;
    }
  };

  if (nb <= 2) core(std::integral_constant<int, 2>{});
  else         core(std::integral_constant<int, 8>{});
}

// ---------------------------------------------------------------------------
// Kernel C: EEG readout, 4 waves split the n-dimension.
// ---------------------------------------------------------------------------
__global__ __launch_bounds__(256) void eeg_kernel(
    const float* __restrict__ lm, const float* __restrict__ vsnap,
    const float* __restrict__ theta, float* __restrict__ out) {
  int tr = blockIdx.x;
  __shared__ float cm[NODE];
  __shared__ float vs[NODE];
  __shared__ float partl[4][OUT];
  int tid = threadIdx.x;
  for (int n = tid; n < NODE; n += 256) {
    float s = 0.f;
    for (int o = 0; o < OUT; ++o) s += lm[o * NODE + n];
    cm[n] = s * (1.f / OUT);
    vs[n] = vsnap[tr * NODE + n];
  }
  __syncthreads();
  int o = tid & 63, w = tid >> 6;
  float acc = 0.f;
  for (int n = w * 100; n < w * 100 + 100; ++n)
    acc = fmaf(lm[o * NODE + n] - cm[n], vs[n], acc);
  partl[w][o] = acc;
  __syncthreads();
  if (tid < OUT) {
    float cy0 = theta[22], y0 = theta[19];
    out[tr * OUT + tid] =
        cy0 * (partl[0][tid] + partl[1][tid] + partl[2][tid] + partl[3][tid]) - y0;
  }
}

extern "C" void kernel_launch(void* const* d_in, const int* in_sizes, int n_in,
                              void* d_out, int out_size, void* d_ws, size_t ws_size,
                              hipStream_t stream) {
  const float* external = (const float*)d_in[0];
  const float* hx       = (const float*)d_in[1];
  const float* hE       = (const float*)d_in[2];
  const float* sc       = (const float*)d_in[3];
  const float* dist     = (const float*)d_in[4];
  const float* wbb      = (const float*)d_in[5];
  const float* wff      = (const float*)d_in[6];
  const float* wll      = (const float*)d_in[7];
  const float* lm       = (const float*)d_in[8];
  const float* theta    = (const float*)d_in[9];
  float* out = (float*)d_out;

  float* vsnap = (float*)d_ws;               // TRS*NODE
  float* part  = vsnap + TRS * NODE;         // 3*64 ssq partials

  ssq_kernel<<<64, 256, 0, stream>>>(wbb, wff, wll, sc, part);
  sim_kernel<<<NODE, 64, 0, stream>>>(external, hx, hE, sc, dist, wbb, wff, wll,
                                      theta, part, vsnap);
  eeg_kernel<<<TRS, 256, 0, stream>>>(lm, vsnap, theta, out);
}